// Round 3
// baseline (3392.850 us; speedup 1.0000x reference)
//
#include <hip/hip_runtime.h>

// GNNCASimple — fp32 I/O + fp32 compute, fused-Wz structure, ws ≈ 187 MB.
// Per step: p = relu(h@W_pre+b), q = relu(p@W_conv+b)@Wz (Wz=W_post[:256]),
//           zq = segsum(q[src] by dst), h' = zq + p@Wp2 + b_post (Wp2=W_post[256:]).
// CSR built once per launch (counting sort by dst).

#define NN 100000
#define FS 64
#define HH 256
#define NE 1600000
#define NSTEPS 4

static __device__ __forceinline__ float4 ld4(const float* p) { return *(const float4*)p; }

// ---------------- CSR build ----------------
__global__ void zero_int_k(int* __restrict__ p, int n) {
    int i = blockIdx.x * 256 + threadIdx.x;
    if (i < n) p[i] = 0;
}

__global__ void hist_k(const int* __restrict__ dst, int* __restrict__ cnt) {
    int e = blockIdx.x * 256 + threadIdx.x;
    if (e < NE) atomicAdd(&cnt[dst[e]], 1);
}

__global__ void scan1_k(const int* __restrict__ cnt, int* __restrict__ part, int* __restrict__ sums) {
    __shared__ int sh[256];
    const int t = threadIdx.x;
    const int base = blockIdx.x * 1024 + t * 4;
    int v0 = (base + 0 < NN) ? cnt[base + 0] : 0;
    int v1 = (base + 1 < NN) ? cnt[base + 1] : 0;
    int v2 = (base + 2 < NN) ? cnt[base + 2] : 0;
    int v3 = (base + 3 < NN) ? cnt[base + 3] : 0;
    int s = v0 + v1 + v2 + v3;
    sh[t] = s;
    __syncthreads();
    for (int o = 1; o < 256; o <<= 1) {
        int y = (t >= o) ? sh[t - o] : 0;
        __syncthreads();
        sh[t] += y;
        __syncthreads();
    }
    int ex = sh[t] - s;
    if (base + 0 < NN) part[base + 0] = ex; ex += v0;
    if (base + 1 < NN) part[base + 1] = ex; ex += v1;
    if (base + 2 < NN) part[base + 2] = ex; ex += v2;
    if (base + 3 < NN) part[base + 3] = ex;
    if (t == 0) sums[blockIdx.x] = sh[255];
}

__global__ void scan2_k(int* __restrict__ sums, int nb, int* __restrict__ total_out) {
    __shared__ int sh[128];
    const int t = threadIdx.x;
    int v = (t < nb) ? sums[t] : 0;
    sh[t] = v;
    __syncthreads();
    for (int o = 1; o < 128; o <<= 1) {
        int y = (t >= o) ? sh[t - o] : 0;
        __syncthreads();
        sh[t] += y;
        __syncthreads();
    }
    if (t < nb) sums[t] = sh[t] - v;
    if (t == 0) *total_out = sh[127];
}

__global__ void scan3_k(int* __restrict__ part, const int* __restrict__ sums, int* __restrict__ cursor) {
    int i = blockIdx.x * 256 + threadIdx.x;
    if (i < NN) {
        int v = part[i] + sums[i >> 10];
        part[i] = v;
        cursor[i] = v;
    }
}

__global__ void fill_k(const int* __restrict__ dst, const int* __restrict__ src,
                       int* __restrict__ cursor, int* __restrict__ srcs) {
    int e = blockIdx.x * 256 + threadIdx.x;
    if (e < NE) {
        int d = dst[e];
        int pos = atomicAdd(&cursor[d], 1);
        srcs[pos] = src[e];
    }
}

// ---------------- pre MLP: p[N,256] = relu(in[N,64] @ W_pre + b_pre) ----------------
// 64 nodes/block; thread t: cols (t&63)*4, nodes (t>>6)+4i, i=0..15.
__global__ __launch_bounds__(256) void pre_k(const float* __restrict__ in,
                                             const float* __restrict__ W,
                                             const float* __restrict__ bias,
                                             float* __restrict__ out) {
    __shared__ float Ws[32 * HH];   // 32 KB
    __shared__ float As[64 * 32];   // 8 KB
    const int t = threadIdx.x;
    const int nodeBase = blockIdx.x * 64;
    const int t_lo = t & 63, t_hi = t >> 6;
    const int col = t_lo * 4;
    float4 acc[16];
#pragma unroll
    for (int i = 0; i < 16; i++) acc[i] = make_float4(0.f, 0.f, 0.f, 0.f);

    for (int k0 = 0; k0 < FS; k0 += 32) {
        __syncthreads();
        {
            const float4* Wg = (const float4*)(W + (size_t)k0 * HH);
            float4* Wl = (float4*)Ws;
#pragma unroll
            for (int i = 0; i < 8; i++) Wl[t + i * 256] = Wg[t + i * 256];
            float4* Al = (float4*)As;
#pragma unroll
            for (int i = 0; i < 2; i++) {
                int f = t + i * 256;          // 512 float4 = 64 nodes x 8
                int nn = f >> 3, kk = (f & 7) * 4;
                int node = nodeBase + nn;
                float4 v = make_float4(0.f, 0.f, 0.f, 0.f);
                if (node < NN) v = ld4(in + (size_t)node * FS + k0 + kk);
                Al[f] = v;
            }
        }
        __syncthreads();
#pragma unroll
        for (int k = 0; k < 32; k += 4) {
            float4 w0 = ld4(&Ws[(k + 0) * HH + col]);
            float4 w1 = ld4(&Ws[(k + 1) * HH + col]);
            float4 w2 = ld4(&Ws[(k + 2) * HH + col]);
            float4 w3 = ld4(&Ws[(k + 3) * HH + col]);
#pragma unroll
            for (int i = 0; i < 16; i++) {
                int nn = t_hi + (i << 2);
                float4 a = ld4(&As[nn * 32 + k]);  // wave-uniform broadcast
                acc[i].x += a.x * w0.x + a.y * w1.x + a.z * w2.x + a.w * w3.x;
                acc[i].y += a.x * w0.y + a.y * w1.y + a.z * w2.y + a.w * w3.y;
                acc[i].z += a.x * w0.z + a.y * w1.z + a.z * w2.z + a.w * w3.z;
                acc[i].w += a.x * w0.w + a.y * w1.w + a.z * w2.w + a.w * w3.w;
            }
        }
    }
    float4 bv = ld4(bias + col);
#pragma unroll
    for (int i = 0; i < 16; i++) {
        int node = nodeBase + t_hi + (i << 2);
        if (node < NN) {
            float4 r;
            r.x = fmaxf(acc[i].x + bv.x, 0.f);
            r.y = fmaxf(acc[i].y + bv.y, 0.f);
            r.z = fmaxf(acc[i].z + bv.z, 0.f);
            r.w = fmaxf(acc[i].w + bv.w, 0.f);
            *(float4*)&out[(size_t)node * HH + col] = r;
        }
    }
}

// ---------------- fused conv: q[N,64] = relu(p @ W_conv + b_conv) @ Wz ----------------
// Stage 1: m-tile (64x256) in regs; stage 2: LDS round-trip, q-tile = m-tile @ Wz.
__global__ __launch_bounds__(256) void conv_q_k(const float* __restrict__ p,
                                                const float* __restrict__ Wc,
                                                const float* __restrict__ bc,
                                                const float* __restrict__ Wz,
                                                float* __restrict__ q) {
    __shared__ float smem[10240];   // 40 KB, unioned across stages
    float* Ws = smem;               // stage1: [32][256]
    float* As = smem + 8192;        // stage1: [64][32]
    float* ml = smem;               // stage2: [64][68]
    float* Wzs = smem + 64 * 68;    // stage2: [64][64]
    const int t = threadIdx.x;
    const int nodeBase = blockIdx.x * 64;
    const int t_lo = t & 63, t_hi = t >> 6;
    const int col = t_lo * 4;
    float4 acc[16];
#pragma unroll
    for (int i = 0; i < 16; i++) acc[i] = make_float4(0.f, 0.f, 0.f, 0.f);

    for (int k0 = 0; k0 < HH; k0 += 32) {
        __syncthreads();
        {
            const float4* Wg = (const float4*)(Wc + (size_t)k0 * HH);
            float4* Wl = (float4*)Ws;
#pragma unroll
            for (int i = 0; i < 8; i++) Wl[t + i * 256] = Wg[t + i * 256];
            float4* Al = (float4*)As;
#pragma unroll
            for (int i = 0; i < 2; i++) {
                int f = t + i * 256;
                int nn = f >> 3, kk = (f & 7) * 4;
                int node = nodeBase + nn;
                float4 v = make_float4(0.f, 0.f, 0.f, 0.f);
                if (node < NN) v = ld4(p + (size_t)node * HH + k0 + kk);
                Al[f] = v;
            }
        }
        __syncthreads();
#pragma unroll
        for (int k = 0; k < 32; k += 4) {
            float4 w0 = ld4(&Ws[(k + 0) * HH + col]);
            float4 w1 = ld4(&Ws[(k + 1) * HH + col]);
            float4 w2 = ld4(&Ws[(k + 2) * HH + col]);
            float4 w3 = ld4(&Ws[(k + 3) * HH + col]);
#pragma unroll
            for (int i = 0; i < 16; i++) {
                int nn = t_hi + (i << 2);
                float4 a = ld4(&As[nn * 32 + k]);
                acc[i].x += a.x * w0.x + a.y * w1.x + a.z * w2.x + a.w * w3.x;
                acc[i].y += a.x * w0.y + a.y * w1.y + a.z * w2.y + a.w * w3.y;
                acc[i].z += a.x * w0.z + a.y * w1.z + a.z * w2.z + a.w * w3.z;
                acc[i].w += a.x * w0.w + a.y * w1.w + a.z * w2.w + a.w * w3.w;
            }
        }
    }
    // bias + relu -> m values in regs
    {
        float4 bv = ld4(bc + col);
#pragma unroll
        for (int i = 0; i < 16; i++) {
            acc[i].x = fmaxf(acc[i].x + bv.x, 0.f);
            acc[i].y = fmaxf(acc[i].y + bv.y, 0.f);
            acc[i].z = fmaxf(acc[i].z + bv.z, 0.f);
            acc[i].w = fmaxf(acc[i].w + bv.w, 0.f);
        }
    }
    // stage 2: q_tile[64][64] = m_tile[64][256] @ Wz[256][64], chunked by 64 over K
    float4 qacc[4];
#pragma unroll
    for (int i = 0; i < 4; i++) qacc[i] = make_float4(0.f, 0.f, 0.f, 0.f);
    const int cq = (t & 15) * 4;
    const int nq = t >> 4;
    for (int c = 0; c < 4; c++) {
        __syncthreads();
        if ((t_lo >> 4) == c) {            // 64 writer threads own m-cols [64c, 64c+64)
            int cc = col - 64 * c;
#pragma unroll
            for (int i = 0; i < 16; i++) {
                int nn = t_hi + (i << 2);
                *(float4*)&ml[nn * 68 + cc] = acc[i];
            }
        }
        {
            const float4* Wg2 = (const float4*)(Wz + (size_t)(64 * c) * FS);
            float4* Wl2 = (float4*)Wzs;
#pragma unroll
            for (int i = 0; i < 4; i++) Wl2[t + i * 256] = Wg2[t + i * 256];
        }
        __syncthreads();
#pragma unroll
        for (int k = 0; k < 64; k += 4) {
            float4 w0 = ld4(&Wzs[(k + 0) * FS + cq]);
            float4 w1 = ld4(&Wzs[(k + 1) * FS + cq]);
            float4 w2 = ld4(&Wzs[(k + 2) * FS + cq]);
            float4 w3 = ld4(&Wzs[(k + 3) * FS + cq]);
#pragma unroll
            for (int i = 0; i < 4; i++) {
                int nn = nq + (i << 4);
                float4 a = ld4(&ml[nn * 68 + k]);
                qacc[i].x += a.x * w0.x + a.y * w1.x + a.z * w2.x + a.w * w3.x;
                qacc[i].y += a.x * w0.y + a.y * w1.y + a.z * w2.y + a.w * w3.y;
                qacc[i].z += a.x * w0.z + a.y * w1.z + a.z * w2.z + a.w * w3.z;
                qacc[i].w += a.x * w0.w + a.y * w1.w + a.z * w2.w + a.w * w3.w;
            }
        }
    }
#pragma unroll
    for (int i = 0; i < 4; i++) {
        int node = nodeBase + nq + (i << 4);
        if (node < NN) *(float4*)&q[(size_t)node * FS + cq] = qacc[i];
    }
}

// ---------------- aggregation: zq[i,:] = sum_{e: dst=i} q[src_e,:] ----------------
__global__ __launch_bounds__(256) void agg_k(const float* __restrict__ q,
                                             const int* __restrict__ offsets,
                                             const int* __restrict__ srcs,
                                             float* __restrict__ zq) {
    const int wave = threadIdx.x >> 6;
    const int lane = threadIdx.x & 63;
    const int node = blockIdx.x * 4 + wave;
    if (node >= NN) return;
    const int beg = offsets[node], end = offsets[node + 1];
    float acc = 0.f;
    int e = beg;
    for (; e + 1 < end; e += 2) {
        int s0 = srcs[e], s1 = srcs[e + 1];
        acc += q[(size_t)s0 * FS + lane];
        acc += q[(size_t)s1 * FS + lane];
    }
    if (e < end) acc += q[(size_t)srcs[e] * FS + lane];
    zq[(size_t)node * FS + lane] = acc;
}

// ---------------- post: out[N,64] = zq + p @ Wp2 + b_post ----------------
// thread t: cols (t&15)*4, nodes (t>>4)+16i, i=0..3.
__global__ __launch_bounds__(256) void post_k(const float* __restrict__ zq,
                                              const float* __restrict__ p,
                                              const float* __restrict__ Wp2,
                                              const float* __restrict__ bias,
                                              float* __restrict__ out) {
    __shared__ float Ws[64 * FS];   // 16 KB
    __shared__ float As[64 * 68];   // 17 KB
    const int t = threadIdx.x;
    const int nodeBase = blockIdx.x * 64;
    const int cq = (t & 15) * 4;
    const int nq = t >> 4;
    float4 acc[4];
#pragma unroll
    for (int i = 0; i < 4; i++) acc[i] = make_float4(0.f, 0.f, 0.f, 0.f);

    for (int k0 = 0; k0 < HH; k0 += 64) {
        __syncthreads();
        {
            const float4* Wg = (const float4*)(Wp2 + (size_t)k0 * FS);
            float4* Wl = (float4*)Ws;
#pragma unroll
            for (int i = 0; i < 4; i++) Wl[t + i * 256] = Wg[t + i * 256];
#pragma unroll
            for (int i = 0; i < 4; i++) {
                int f = t + i * 256;          // 1024 float4 = 64 nodes x 16
                int nn = f >> 4, kk = (f & 15) * 4;
                int node = nodeBase + nn;
                float4 v = make_float4(0.f, 0.f, 0.f, 0.f);
                if (node < NN) v = ld4(p + (size_t)node * HH + k0 + kk);
                *(float4*)&As[nn * 68 + kk] = v;
            }
        }
        __syncthreads();
#pragma unroll
        for (int k = 0; k < 64; k += 4) {
            float4 w0 = ld4(&Ws[(k + 0) * FS + cq]);
            float4 w1 = ld4(&Ws[(k + 1) * FS + cq]);
            float4 w2 = ld4(&Ws[(k + 2) * FS + cq]);
            float4 w3 = ld4(&Ws[(k + 3) * FS + cq]);
#pragma unroll
            for (int i = 0; i < 4; i++) {
                int nn = nq + (i << 4);
                float4 a = ld4(&As[nn * 68 + k]);
                acc[i].x += a.x * w0.x + a.y * w1.x + a.z * w2.x + a.w * w3.x;
                acc[i].y += a.x * w0.y + a.y * w1.y + a.z * w2.y + a.w * w3.y;
                acc[i].z += a.x * w0.z + a.y * w1.z + a.z * w2.z + a.w * w3.z;
                acc[i].w += a.x * w0.w + a.y * w1.w + a.z * w2.w + a.w * w3.w;
            }
        }
    }
    float4 bv = ld4(bias + cq);
#pragma unroll
    for (int i = 0; i < 4; i++) {
        int node = nodeBase + nq + (i << 4);
        if (node < NN) {
            float4 zz = ld4(&zq[(size_t)node * FS + cq]);
            float4 r;
            r.x = acc[i].x + zz.x + bv.x;
            r.y = acc[i].y + zz.y + bv.y;
            r.z = acc[i].z + zz.z + bv.z;
            r.w = acc[i].w + zz.w + bv.w;
            *(float4*)&out[(size_t)node * FS + cq] = r;
        }
    }
}

extern "C" void kernel_launch(void* const* d_in, const int* in_sizes, int n_in,
                              void* d_out, int out_size, void* d_ws, size_t ws_size,
                              hipStream_t stream) {
    const float* x      = (const float*)d_in[0];
    const int*   ei     = (const int*)d_in[1];
    const float* W_pre  = (const float*)d_in[2];
    const float* b_pre  = (const float*)d_in[3];
    const float* W_conv = (const float*)d_in[4];
    const float* b_conv = (const float*)d_in[5];
    const float* W_post = (const float*)d_in[6];
    const float* b_post = (const float*)d_in[7];
    float* out = (float*)d_out;

    char* ws = (char*)d_ws;
    size_t off = 0;
    auto alloc = [&](size_t bytes) -> char* {
        char* r = ws + off;
        off += (bytes + 255) & ~(size_t)255;
        return r;
    };
    // Total ws use ≈ 187 MB (round-1 footprint ran without fault; round-0's 340 MB faulted).
    float* p       = (float*)alloc((size_t)NN * HH * 4);   // 102.4 MB
    float* q       = (float*)alloc((size_t)NN * FS * 4);   //  25.6 MB
    float* zq      = (float*)alloc((size_t)NN * FS * 4);   //  25.6 MB
    float* h       = (float*)alloc((size_t)NN * FS * 4);   //  25.6 MB
    int*   offsets = (int*)alloc((size_t)(NN + 1) * 4);
    int*   cursor  = (int*)alloc((size_t)NN * 4);
    int*   srcs    = (int*)alloc((size_t)NE * 4);          //   6.4 MB
    int*   sums    = (int*)alloc(128 * 4);
    (void)ws_size; (void)in_sizes; (void)n_in; (void)out_size;

    const int* dst = ei;       // edge_index[0] = aggregation targets
    const int* src = ei + NE;  // edge_index[1] = message sources

    // CSR build
    zero_int_k<<<(NN + 255) / 256, 256, 0, stream>>>(cursor, NN);
    hist_k<<<(NE + 255) / 256, 256, 0, stream>>>(dst, cursor);
    const int NB = (NN + 1023) / 1024;  // 98
    scan1_k<<<NB, 256, 0, stream>>>(cursor, offsets, sums);
    scan2_k<<<1, 128, 0, stream>>>(sums, NB, offsets + NN);
    scan3_k<<<(NN + 255) / 256, 256, 0, stream>>>(offsets, sums, cursor);
    fill_k<<<(NE + 255) / 256, 256, 0, stream>>>(dst, src, cursor, srcs);

    const float* Wz  = W_post;              // rows [0,256)
    const float* Wp2 = W_post + 256 * FS;   // rows [256,512)

    const int GB = (NN + 63) / 64;  // 1563
    for (int s = 0; s < NSTEPS; s++) {
        const float* hin = (s == 0) ? x : h;
        pre_k<<<GB, 256, 0, stream>>>(hin, W_pre, b_pre, p);
        conv_q_k<<<GB, 256, 0, stream>>>(p, W_conv, b_conv, Wz, q);
        agg_k<<<NN / 4, 256, 0, stream>>>(q, offsets, srcs, zq);
        float* hout = (s == NSTEPS - 1) ? out : h;
        post_k<<<GB, 256, 0, stream>>>(zq, p, Wp2, b_post, hout);
    }
}

// Round 4
// 1096.726 us; speedup vs baseline: 3.0936x; 3.0936x over previous
//
#include <hip/hip_runtime.h>

// GNNCASimple — bf16-MFMA GEMMs (fp32 accumulate), fp32 I/O.
// Per step: p = relu(h@W_pre+b), q = relu(p@W_conv+b)@Wz (Wz=W_post[:256]),
//           zq = segsum(q[src] by dst), h' = zq + p@Wp2 + b_post (Wp2=W_post[256:]).
// All GEMM inputs rounded to bf16; weights pre-transposed to [col][k] bf16 once.
// CSR built once per launch (counting sort by dst).

#define NN 100000
#define NPAD 100064   // +64 rows so MFMA fragment loads of the tail block stay in-bounds
#define FS 64
#define HH 256
#define NE 1600000
#define NSTEPS 4

typedef unsigned short u16;
typedef unsigned int u32;
typedef __attribute__((ext_vector_type(8))) short bfrag;   // 8 bf16 = 4 VGPRs (MFMA A/B)
typedef __attribute__((ext_vector_type(4))) float ffrag;   // 4 fp32 (MFMA C/D)

static __device__ __forceinline__ u16 f2bf(float f) {  // RNE
    union { float f; u32 u; } v; v.f = f;
    return (u16)((v.u + 0x7fffu + ((v.u >> 16) & 1u)) >> 16);
}
static __device__ __forceinline__ float bf2f(u16 h) {
    union { u32 u; float f; } v; v.u = (u32)h << 16; return v.f;
}

// ---------------- x (fp32) -> h (bf16) ----------------
__global__ void cvt_x_k(const float4* __restrict__ x, uint2* __restrict__ hbf, int n4) {
    int i = blockIdx.x * 256 + threadIdx.x;
    if (i < n4) {
        float4 v = x[i];
        uint2 o;
        o.x = (u32)f2bf(v.x) | ((u32)f2bf(v.y) << 16);
        o.y = (u32)f2bf(v.z) | ((u32)f2bf(v.w) << 16);
        hbf[i] = o;
    }
}

// ---------------- W [K][C] fp32 -> Wt [C][K] bf16 ----------------
template <int LK, int LC>
__global__ void transpose_cvt_k(const float* __restrict__ W, u16* __restrict__ Wt) {
    const int K = 1 << LK, C = 1 << LC;
    int i = blockIdx.x * 256 + threadIdx.x;
    if (i < K * C) {
        int c = i >> LK, k = i & (K - 1);
        Wt[i] = f2bf(W[(size_t)k * C + c]);
    }
}

// ---------------- CSR build ----------------
__global__ void zero_int_k(int* __restrict__ p, int n) {
    int i = blockIdx.x * 256 + threadIdx.x;
    if (i < n) p[i] = 0;
}

__global__ void hist_k(const int* __restrict__ dst, int* __restrict__ cnt) {
    int e = blockIdx.x * 256 + threadIdx.x;
    if (e < NE) atomicAdd(&cnt[dst[e]], 1);
}

__global__ void scan1_k(const int* __restrict__ cnt, int* __restrict__ part, int* __restrict__ sums) {
    __shared__ int sh[256];
    const int t = threadIdx.x;
    const int base = blockIdx.x * 1024 + t * 4;
    int v0 = (base + 0 < NN) ? cnt[base + 0] : 0;
    int v1 = (base + 1 < NN) ? cnt[base + 1] : 0;
    int v2 = (base + 2 < NN) ? cnt[base + 2] : 0;
    int v3 = (base + 3 < NN) ? cnt[base + 3] : 0;
    int s = v0 + v1 + v2 + v3;
    sh[t] = s;
    __syncthreads();
    for (int o = 1; o < 256; o <<= 1) {
        int y = (t >= o) ? sh[t - o] : 0;
        __syncthreads();
        sh[t] += y;
        __syncthreads();
    }
    int ex = sh[t] - s;
    if (base + 0 < NN) part[base + 0] = ex; ex += v0;
    if (base + 1 < NN) part[base + 1] = ex; ex += v1;
    if (base + 2 < NN) part[base + 2] = ex; ex += v2;
    if (base + 3 < NN) part[base + 3] = ex;
    if (t == 0) sums[blockIdx.x] = sh[255];
}

__global__ void scan2_k(int* __restrict__ sums, int nb, int* __restrict__ total_out) {
    __shared__ int sh[128];
    const int t = threadIdx.x;
    int v = (t < nb) ? sums[t] : 0;
    sh[t] = v;
    __syncthreads();
    for (int o = 1; o < 128; o <<= 1) {
        int y = (t >= o) ? sh[t - o] : 0;
        __syncthreads();
        sh[t] += y;
        __syncthreads();
    }
    if (t < nb) sums[t] = sh[t] - v;
    if (t == 0) *total_out = sh[127];
}

__global__ void scan3_k(int* __restrict__ part, const int* __restrict__ sums, int* __restrict__ cursor) {
    int i = blockIdx.x * 256 + threadIdx.x;
    if (i < NN) {
        int v = part[i] + sums[i >> 10];
        part[i] = v;
        cursor[i] = v;
    }
}

__global__ void fill_k(const int* __restrict__ dst, const int* __restrict__ src,
                       int* __restrict__ cursor, int* __restrict__ srcs) {
    int e = blockIdx.x * 256 + threadIdx.x;
    if (e < NE) {
        int d = dst[e];
        int pos = atomicAdd(&cursor[d], 1);
        srcs[pos] = src[e];
    }
}

// ---------------- pre MLP: p[N,256] = relu(h[N,64] @ W_pre + b_pre), bf16 out ----------------
// 64 nodes/block, 4 waves; wave w owns output cols [64w, 64w+64).
__global__ __launch_bounds__(256) void pre_k(const u16* __restrict__ hbf,   // [NPAD][64]
                                             const u16* __restrict__ Wpt,   // [256][64] (col-major-T)
                                             const float* __restrict__ bias,
                                             u16* __restrict__ pbf) {       // [NPAD][256]
    const int t = threadIdx.x;
    const int wave = t >> 6, lane = t & 63;
    const int quad = lane >> 4, l16 = lane & 15;
    const int nodeBase = blockIdx.x * 64;
    ffrag acc[4][4];
#pragma unroll
    for (int mt = 0; mt < 4; mt++)
#pragma unroll
        for (int nt = 0; nt < 4; nt++) acc[mt][nt] = (ffrag)0.f;

#pragma unroll
    for (int ch = 0; ch < 2; ch++) {
        const int kb = ch * 32 + quad * 8;
        bfrag a[4], b[4];
#pragma unroll
        for (int mt = 0; mt < 4; mt++)
            a[mt] = *(const bfrag*)(hbf + (size_t)(nodeBase + mt * 16 + l16) * FS + kb);
#pragma unroll
        for (int nt = 0; nt < 4; nt++)
            b[nt] = *(const bfrag*)(Wpt + (size_t)(wave * 64 + nt * 16 + l16) * FS + kb);
#pragma unroll
        for (int mt = 0; mt < 4; mt++)
#pragma unroll
            for (int nt = 0; nt < 4; nt++)
                acc[mt][nt] = __builtin_amdgcn_mfma_f32_16x16x32_bf16(a[mt], b[nt], acc[mt][nt], 0, 0, 0);
    }
#pragma unroll
    for (int nt = 0; nt < 4; nt++) {
        const int col = wave * 64 + nt * 16 + l16;
        const float bv = bias[col];
#pragma unroll
        for (int mt = 0; mt < 4; mt++)
#pragma unroll
            for (int r = 0; r < 4; r++) {
                int node = nodeBase + mt * 16 + quad * 4 + r;
                if (node < NN) pbf[(size_t)node * HH + col] = f2bf(fmaxf(acc[mt][nt][r] + bv, 0.f));
            }
    }
}

// ---------------- fused conv: q[N,64] = relu(p @ W_conv + b_conv) @ Wz, bf16 out ----------------
__global__ __launch_bounds__(256) void conv_q_k(const u16* __restrict__ pbf,  // [NPAD][256]
                                                const u16* __restrict__ Wct,  // [256][256]
                                                const float* __restrict__ bc,
                                                const u16* __restrict__ Wzt,  // [64][256]
                                                u16* __restrict__ qbf) {      // [NN][64]
    __shared__ u16 ml[64 * 264];  // m-tile bf16, stride 264 (16B-aligned, conflict-breaking)
    const int t = threadIdx.x;
    const int wave = t >> 6, lane = t & 63;
    const int quad = lane >> 4, l16 = lane & 15;
    const int nodeBase = blockIdx.x * 64;

    // stage 1: m-tile[64][256] = relu(p-tile @ Wc + bc); wave w owns m-cols [64w, 64w+64)
    ffrag acc[4][4];
#pragma unroll
    for (int mt = 0; mt < 4; mt++)
#pragma unroll
        for (int nt = 0; nt < 4; nt++) acc[mt][nt] = (ffrag)0.f;

#pragma unroll
    for (int ch = 0; ch < 8; ch++) {
        const int kb = ch * 32 + quad * 8;
        bfrag a[4], b[4];
#pragma unroll
        for (int mt = 0; mt < 4; mt++)
            a[mt] = *(const bfrag*)(pbf + (size_t)(nodeBase + mt * 16 + l16) * HH + kb);
#pragma unroll
        for (int nt = 0; nt < 4; nt++)
            b[nt] = *(const bfrag*)(Wct + (size_t)(wave * 64 + nt * 16 + l16) * HH + kb);
#pragma unroll
        for (int mt = 0; mt < 4; mt++)
#pragma unroll
            for (int nt = 0; nt < 4; nt++)
                acc[mt][nt] = __builtin_amdgcn_mfma_f32_16x16x32_bf16(a[mt], b[nt], acc[mt][nt], 0, 0, 0);
    }
    // epilogue: bias + relu -> bf16 into LDS
#pragma unroll
    for (int nt = 0; nt < 4; nt++) {
        const int col = wave * 64 + nt * 16 + l16;
        const float bv = bc[col];
#pragma unroll
        for (int mt = 0; mt < 4; mt++)
#pragma unroll
            for (int r = 0; r < 4; r++) {
                int nl = mt * 16 + quad * 4 + r;
                ml[nl * 264 + col] = f2bf(fmaxf(acc[mt][nt][r] + bv, 0.f));
            }
    }
    __syncthreads();

    // stage 2: q-tile[64][64] = m-tile @ Wz; wave w owns q-cols [16w, 16w+16)
    ffrag qa[4];
#pragma unroll
    for (int mt = 0; mt < 4; mt++) qa[mt] = (ffrag)0.f;
#pragma unroll
    for (int ch = 0; ch < 8; ch++) {
        const int kb = ch * 32 + quad * 8;
        bfrag bz = *(const bfrag*)(Wzt + (size_t)(wave * 16 + l16) * HH + kb);
#pragma unroll
        for (int mt = 0; mt < 4; mt++) {
            bfrag am = *(const bfrag*)(ml + (mt * 16 + l16) * 264 + kb);
            qa[mt] = __builtin_amdgcn_mfma_f32_16x16x32_bf16(am, bz, qa[mt], 0, 0, 0);
        }
    }
    const int col = wave * 16 + l16;
#pragma unroll
    for (int mt = 0; mt < 4; mt++)
#pragma unroll
        for (int r = 0; r < 4; r++) {
            int node = nodeBase + mt * 16 + quad * 4 + r;
            if (node < NN) qbf[(size_t)node * FS + col] = f2bf(qa[mt][r]);
        }
}

// ---------------- aggregation: zq[i,:] = sum_{e: dst=i} q[src_e,:] (bf16 q, fp32 zq) ----------------
__global__ __launch_bounds__(256) void agg_k(const u32* __restrict__ q2,  // [NN][32] packed bf16 pairs
                                             const int* __restrict__ offsets,
                                             const int* __restrict__ srcs,
                                             float* __restrict__ zq) {
    const int wave = threadIdx.x >> 6;
    const int lane = threadIdx.x & 63;
    const int node = blockIdx.x * 4 + wave;
    const int half = lane >> 5, c = lane & 31;
    const int beg = offsets[node], end = offsets[node + 1];
    float ax = 0.f, ay = 0.f;
    int e = beg + half;
    for (; e + 2 < end; e += 4) {
        u32 g0 = q2[(size_t)srcs[e] * 32 + c];
        u32 g1 = q2[(size_t)srcs[e + 2] * 32 + c];
        ax += bf2f((u16)g0) + bf2f((u16)g1);
        ay += bf2f((u16)(g0 >> 16)) + bf2f((u16)(g1 >> 16));
    }
    for (; e < end; e += 2) {
        u32 g = q2[(size_t)srcs[e] * 32 + c];
        ax += bf2f((u16)g);
        ay += bf2f((u16)(g >> 16));
    }
    ax += __shfl_xor(ax, 32);
    ay += __shfl_xor(ay, 32);
    if (half == 0) {
        float2 o = make_float2(ax, ay);
        *(float2*)&zq[(size_t)node * FS + 2 * c] = o;
    }
}

// ---------------- post: out[N,64] = zq + p @ Wp2 + b_post ----------------
template <bool LAST>
__global__ __launch_bounds__(256) void post_k(const float* __restrict__ zq,
                                              const u16* __restrict__ pbf,   // [NPAD][256]
                                              const u16* __restrict__ Wp2t,  // [64][256]
                                              const float* __restrict__ bias,
                                              u16* __restrict__ hbf,         // [NPAD][64]
                                              float* __restrict__ outf) {
    const int t = threadIdx.x;
    const int wave = t >> 6, lane = t & 63;
    const int quad = lane >> 4, l16 = lane & 15;
    const int nodeBase = blockIdx.x * 64;
    ffrag acc[4];
#pragma unroll
    for (int mt = 0; mt < 4; mt++) acc[mt] = (ffrag)0.f;

#pragma unroll
    for (int ch = 0; ch < 8; ch++) {
        const int kb = ch * 32 + quad * 8;
        bfrag b = *(const bfrag*)(Wp2t + (size_t)(wave * 16 + l16) * HH + kb);
#pragma unroll
        for (int mt = 0; mt < 4; mt++) {
            bfrag a = *(const bfrag*)(pbf + (size_t)(nodeBase + mt * 16 + l16) * HH + kb);
            acc[mt] = __builtin_amdgcn_mfma_f32_16x16x32_bf16(a, b, acc[mt], 0, 0, 0);
        }
    }
    const int col = wave * 16 + l16;
    const float bv = bias[col];
#pragma unroll
    for (int mt = 0; mt < 4; mt++)
#pragma unroll
        for (int r = 0; r < 4; r++) {
            int node = nodeBase + mt * 16 + quad * 4 + r;
            if (node < NN) {
                float v = acc[mt][r] + zq[(size_t)node * FS + col] + bv;
                if (LAST) outf[(size_t)node * FS + col] = v;
                else      hbf[(size_t)node * FS + col] = f2bf(v);
            }
        }
}

extern "C" void kernel_launch(void* const* d_in, const int* in_sizes, int n_in,
                              void* d_out, int out_size, void* d_ws, size_t ws_size,
                              hipStream_t stream) {
    const float* x      = (const float*)d_in[0];
    const int*   ei     = (const int*)d_in[1];
    const float* W_pre  = (const float*)d_in[2];
    const float* b_pre  = (const float*)d_in[3];
    const float* W_conv = (const float*)d_in[4];
    const float* b_conv = (const float*)d_in[5];
    const float* W_post = (const float*)d_in[6];
    const float* b_post = (const float*)d_in[7];
    float* out = (float*)d_out;

    char* ws = (char*)d_ws;
    size_t off = 0;
    auto alloc = [&](size_t bytes) -> char* {
        char* r = ws + off;
        off += (bytes + 255) & ~(size_t)255;
        return r;
    };
    u16* pbf     = (u16*)alloc((size_t)NPAD * HH * 2);  // 51.2 MB
    u16* hbf     = (u16*)alloc((size_t)NPAD * FS * 2);  // 12.8 MB
    u16* qbf     = (u16*)alloc((size_t)NN * FS * 2);    // 12.8 MB
    float* zq    = (float*)alloc((size_t)NN * FS * 4);  // 25.6 MB
    int* offsets = (int*)alloc((size_t)(NN + 1) * 4);
    int* cursor  = (int*)alloc((size_t)NN * 4);
    int* srcs    = (int*)alloc((size_t)NE * 4);         // 6.4 MB
    int* sums    = (int*)alloc(128 * 4);
    u16* Wpt     = (u16*)alloc((size_t)HH * FS * 2);    // [256][64]
    u16* Wct     = (u16*)alloc((size_t)HH * HH * 2);    // [256][256]
    u16* Wzt     = (u16*)alloc((size_t)FS * HH * 2);    // [64][256]
    u16* Wp2t    = (u16*)alloc((size_t)FS * HH * 2);    // [64][256]
    (void)ws_size; (void)in_sizes; (void)n_in; (void)out_size;

    const int* dst = ei;       // edge_index[0] = aggregation targets
    const int* src = ei + NE;  // edge_index[1] = message sources

    // input casts / weight transposes
    cvt_x_k<<<(NN * FS / 4 + 255) / 256, 256, 0, stream>>>((const float4*)x, (uint2*)hbf, NN * FS / 4);
    transpose_cvt_k<6, 8><<<(HH * FS + 255) / 256, 256, 0, stream>>>(W_pre, Wpt);           // K=64,C=256
    transpose_cvt_k<8, 8><<<(HH * HH + 255) / 256, 256, 0, stream>>>(W_conv, Wct);          // K=256,C=256
    transpose_cvt_k<8, 6><<<(HH * FS + 255) / 256, 256, 0, stream>>>(W_post, Wzt);          // rows [0,256)
    transpose_cvt_k<8, 6><<<(HH * FS + 255) / 256, 256, 0, stream>>>(W_post + HH * FS, Wp2t);  // rows [256,512)

    // CSR build
    zero_int_k<<<(NN + 255) / 256, 256, 0, stream>>>(cursor, NN);
    hist_k<<<(NE + 255) / 256, 256, 0, stream>>>(dst, cursor);
    const int NB = (NN + 1023) / 1024;  // 98
    scan1_k<<<NB, 256, 0, stream>>>(cursor, offsets, sums);
    scan2_k<<<1, 128, 0, stream>>>(sums, NB, offsets + NN);
    scan3_k<<<(NN + 255) / 256, 256, 0, stream>>>(offsets, sums, cursor);
    fill_k<<<(NE + 255) / 256, 256, 0, stream>>>(dst, src, cursor, srcs);

    const int GB = (NN + 63) / 64;  // 1563
    for (int s = 0; s < NSTEPS; s++) {
        pre_k<<<GB, 256, 0, stream>>>(hbf, Wpt, b_pre, pbf);
        conv_q_k<<<GB, 256, 0, stream>>>(pbf, Wct, b_conv, Wzt, qbf);
        agg_k<<<NN / 4, 256, 0, stream>>>((const u32*)qbf, offsets, srcs, zq);
        if (s < NSTEPS - 1)
            post_k<false><<<GB, 256, 0, stream>>>(zq, pbf, Wp2t, b_post, hbf, nullptr);
        else
            post_k<true><<<GB, 256, 0, stream>>>(zq, pbf, Wp2t, b_post, nullptr, out);
    }
}